// Round 7
// baseline (1996.426 us; speedup 1.0000x reference)
//
#include <hip/hip_runtime.h>
#include <hip/hip_bf16.h>

// VQ-VAE VectorQuantizer forward, MI355X — round 4 (resubmit x3): 3-buffer counted-vmcnt MFMA GEMM.
//
// Precision contract (validated: round-3 absmax = 0.0 bitwise):
//  - argmin over d_k = fl(S - 2*dot_k)   [E_k vanishes: E_max=3.8e-6 < ulp(S)/2]
//  - dot via 3-product fp16 split (K_eff=768): err ~7e-9 abs << ulp(d)=3e-5
//  - dot = acc * 2^-13 exact (B pre-scaled by 2^13); S fp64-accumulated, c-ascending
//
// dist kernel schedule (T3+T4+T5, race-free by construction):
//  - BM=128 (tokens) x BN=256 (codes), BK=64, 512 thr / 8 waves (2x4), 12 K-steps
//  - 3 LDS buffers (48KB each): group g reads buf[g%3], stages K(g+2) into
//    buf[(g+2)%3] — never a buffer being read, regardless of landing time.
//  - 2 phases/group, 16 MFMA each, raw s_barrier + counted vmcnt(6) (never 0
//    mid-loop), lgkmcnt(0)+sched_barrier before MFMA, setprio(1) around MFMA.
//  - XOR swizzle byte^=((row&7)<<4) on ds_read; inverse-swizzled global source
//    for linear global_load_lds (round-3: SQ_LDS_BANK_CONFLICT == 0).

#define TOK   32768
#define KCB   8192
#define CDIM  256

#define LOSS_OFF   8388608
#define PERP_OFF   8388609
#define OH_OFF     8388610
#define OH_ELEMS   268435456
#define IDX_OFF    276824066

#define NTILES_K   32   // 8192/256 code tiles

typedef _Float16 f16x8 __attribute__((ext_vector_type(8)));
typedef _Float16 f16x4 __attribute__((ext_vector_type(4)));
typedef float    f32x4 __attribute__((ext_vector_type(4)));

#define BSCALE     8192.0f     // 2^13
#define BSCALE_INV 0x1p-13f

__device__ __forceinline__ void gload16(const void* g, void* l) {
    __builtin_amdgcn_global_load_lds(
        (const __attribute__((address_space(1))) void*)g,
        (__attribute__((address_space(3))) void*)l, 16, 0, 0);
}

// ---------------- S[n] = sum_c x^2, fp64 accum (c ascending, bit-stable) ----
__global__ __launch_bounds__(256) void s_kernel(const float* __restrict__ x,
                                                float* __restrict__ S) {
    int n = blockIdx.x * 256 + threadIdx.x;
    int b = n >> 10, hw = n & 1023;
    const float* p = x + (size_t)b * 262144 + hw;
    double s = 0.0;
    #pragma unroll 8
    for (int c = 0; c < CDIM; ++c) {
        float v = p[(size_t)c * 1024];
        s += (double)v * (double)v;
    }
    S[n] = (float)s;
}

// ---------------- x -> A16 [32768][512] fp16 (xhi | xlo), transposed --------
__global__ __launch_bounds__(256) void split_x_kernel(const float* __restrict__ x,
                                                      _Float16* __restrict__ A16) {
    __shared__ float xs[64][65];
    const int n0 = blockIdx.x * 64;
    const int b = n0 >> 10, hw0 = n0 & 1023;
    const float* xb = x + (size_t)b * 262144 + hw0;
    const int cr = threadIdx.x >> 6, i = threadIdx.x & 63;
    const int tl = threadIdx.x >> 2, part = threadIdx.x & 3;

    for (int ch = 0; ch < 4; ++ch) {
        const int c0 = ch * 64;
        __syncthreads();
        #pragma unroll
        for (int j = 0; j < 16; ++j)
            xs[cr * 16 + j][i] = xb[(size_t)(c0 + cr * 16 + j) * 1024 + i];
        __syncthreads();
        f16x8 h0, h1, l0, l1;
        #pragma unroll
        for (int j = 0; j < 8; ++j) {
            float v = xs[part * 16 + j][tl];
            _Float16 h = (_Float16)v;
            h0[j] = h; l0[j] = (_Float16)(v - (float)h);
        }
        #pragma unroll
        for (int j = 0; j < 8; ++j) {
            float v = xs[part * 16 + 8 + j][tl];
            _Float16 h = (_Float16)v;
            h1[j] = h; l1[j] = (_Float16)(v - (float)h);
        }
        _Float16* dst = A16 + (size_t)(n0 + tl) * 512 + c0 + part * 16;
        *(f16x8*)(dst)           = h0;
        *(f16x8*)(dst + 8)       = h1;
        *(f16x8*)(dst + 256)     = l0;
        *(f16x8*)(dst + 256 + 8) = l1;
    }
}

// ---------------- cb -> B16 [8192][512] fp16 (ehi*2^13 | elo*2^13) ----------
__global__ __launch_bounds__(256) void split_cb_kernel(const float* __restrict__ cb,
                                                       _Float16* __restrict__ B16) {
    int t = blockIdx.x * 256 + threadIdx.x;
    int code = t >> 6, c = (t & 63) * 4;
    float4 v = *(const float4*)(cb + (size_t)code * 256 + c);
    float ev[4] = {v.x * BSCALE, v.y * BSCALE, v.z * BSCALE, v.w * BSCALE};
    f16x4 h, l;
    #pragma unroll
    for (int j = 0; j < 4; ++j) {
        _Float16 hh = (_Float16)ev[j];
        h[j] = hh; l[j] = (_Float16)(ev[j] - (float)hh);
    }
    *(f16x4*)(B16 + (size_t)code * 512 + c)       = h;
    *(f16x4*)(B16 + (size_t)code * 512 + 256 + c) = l;
}

// ---------------- MFMA distance GEMM + fused argmin -------------------------
__global__ __launch_bounds__(512, 2) void dist_mfma_kernel(
        const _Float16* __restrict__ A16, const _Float16* __restrict__ B16,
        const float* __restrict__ S,
        float* __restrict__ pd, int* __restrict__ pi) {
    __shared__ char smem[147456];          // 3 x (A 16KB + B 32KB)

    const int tid  = threadIdx.x;
    const int lane = tid & 63, w = tid >> 6;
    const int wr = w >> 2, wc = w & 3;     // 2 x 4 waves

    // XCD-aware bijective swizzle (nwg = 8192 = 8*1024); code-tile-major per
    // XCD so each XCD's B panel (4 tiles = 1MB) stays L2-resident.
    const int id  = (int)(blockIdx.y * gridDim.x + blockIdx.x);   // 0..8191
    const int nid = (id & 7) * 1024 + (id >> 3);
    const int bxt = nid >> 8;              // code tile 0..31
    const int byt = nid & 255;             // token tile 0..255
    const int m0  = byt * 128;
    const int n0  = bxt * 256;

    const char* A16b = (const char*)A16;
    const char* B16b = (const char*)B16;

    // staging constants: thread stages 16B of row srow(+64k), source chunk
    // inverse-swizzled so linear LDS + swizzled read line up (rule 21).
    const int srow     = tid >> 3;                      // 0..63
    const int schunk16 = ((tid & 7) ^ (srow & 7)) << 4; // byte offset in row

    // ds_read swizzled slot: row&7 == lane&7 for all fragments (16-row frags)
    const int lr  = lane & 15;             // row-in-frag
    const int l47 = lane & 7;
    const int lhi = lane >> 4;             // 0..3

    f32x4 acc[4][4] = {};

    // -------- prologue: stage K-steps 0 and 1 (buf 0, 1) --------
    #pragma unroll
    for (int s = 0; s < 2; ++s) {
        const int aK2 = s * 128, bK2 = s * 128;        // byte offsets (steps 0,1: hi|hi)
        char* Ab = smem + s * 49152;
        char* Bb = Ab + 16384;
        gload16(A16b + (size_t)(m0 + srow)      * 1024 + aK2 + schunk16, Ab + tid * 16);
        gload16(A16b + (size_t)(m0 + 64 + srow) * 1024 + aK2 + schunk16, Ab + 8192 + tid * 16);
        #pragma unroll
        for (int i = 0; i < 4; ++i)
            gload16(B16b + (size_t)(n0 + i * 64 + srow) * 1024 + bK2 + schunk16,
                    Bb + i * 8192 + tid * 16);
    }
    asm volatile("s_waitcnt vmcnt(6)" ::: "memory");   // K0 landed, K1 in flight
    __builtin_amdgcn_sched_barrier(0);
    __builtin_amdgcn_s_barrier();
    __builtin_amdgcn_sched_barrier(0);

    // -------- main loop: 12 K-steps --------
    #pragma unroll
    for (int g = 0; g < 12; ++g) {
        char* Ab = smem + (g % 3) * 49152;
        char* Bb = Ab + 16384;
        const int s2 = g + 2;
        char* Ab2 = smem + (s2 % 3) * 49152;
        char* Bb2 = Ab2 + 16384;
        const int ph2 = s2 >> 2, rk2 = (s2 & 3) * 128;           // stage offsets (bytes)
        const int aK2 = (ph2 == 2 ? 512 : 0) + rk2;
        const int bK2 = (ph2 == 1 ? 512 : 0) + rk2;

        // ---- phase 0: read B(all n) + A(m=0,1); stage A0,A1,B0 of K(g+2) ----
        f16x8 bf[4][2], af[2][2];
        #pragma unroll
        for (int n = 0; n < 4; ++n)
            #pragma unroll
            for (int kk = 0; kk < 2; ++kk) {
                const int row = wc * 64 + n * 16 + lr;
                bf[n][kk] = *(const f16x8*)(Bb + row * 128 + (((kk * 4 + lhi) ^ l47) << 4));
            }
        #pragma unroll
        for (int m = 0; m < 2; ++m)
            #pragma unroll
            for (int kk = 0; kk < 2; ++kk) {
                const int row = wr * 64 + m * 16 + lr;
                af[m][kk] = *(const f16x8*)(Ab + row * 128 + (((kk * 4 + lhi) ^ l47) << 4));
            }
        if (s2 < 12) {
            gload16(A16b + (size_t)(m0 + srow)      * 1024 + aK2 + schunk16, Ab2 + tid * 16);
            gload16(A16b + (size_t)(m0 + 64 + srow) * 1024 + aK2 + schunk16, Ab2 + 8192 + tid * 16);
            gload16(B16b + (size_t)(n0 + srow)      * 1024 + bK2 + schunk16, Bb2 + tid * 16);
        }
        __builtin_amdgcn_s_barrier();
        asm volatile("s_waitcnt lgkmcnt(0)" ::: "memory");
        __builtin_amdgcn_sched_barrier(0);
        __builtin_amdgcn_s_setprio(1);
        #pragma unroll
        for (int m = 0; m < 2; ++m)
            #pragma unroll
            for (int n = 0; n < 4; ++n)
                #pragma unroll
                for (int kk = 0; kk < 2; ++kk)
                    acc[m][n] = __builtin_amdgcn_mfma_f32_16x16x32_f16(
                        af[m][kk], bf[n][kk], acc[m][n], 0, 0, 0);
        __builtin_amdgcn_s_setprio(0);
        __builtin_amdgcn_sched_barrier(0);
        __builtin_amdgcn_s_barrier();
        __builtin_amdgcn_sched_barrier(0);

        // ---- phase 1: read A(m=2,3); stage B1,B2,B3 of K(g+2) ----
        f16x8 af2[2][2];
        #pragma unroll
        for (int m = 0; m < 2; ++m)
            #pragma unroll
            for (int kk = 0; kk < 2; ++kk) {
                const int row = wr * 64 + (m + 2) * 16 + lr;
                af2[m][kk] = *(const f16x8*)(Ab + row * 128 + (((kk * 4 + lhi) ^ l47) << 4));
            }
        if (s2 < 12) {
            #pragma unroll
            for (int i = 1; i < 4; ++i)
                gload16(B16b + (size_t)(n0 + i * 64 + srow) * 1024 + bK2 + schunk16,
                        Bb2 + i * 8192 + tid * 16);
        }
        __builtin_amdgcn_s_barrier();
        asm volatile("s_waitcnt lgkmcnt(0)" ::: "memory");
        __builtin_amdgcn_sched_barrier(0);
        __builtin_amdgcn_s_setprio(1);
        #pragma unroll
        for (int m = 0; m < 2; ++m)
            #pragma unroll
            for (int n = 0; n < 4; ++n)
                #pragma unroll
                for (int kk = 0; kk < 2; ++kk)
                    acc[m + 2][n] = __builtin_amdgcn_mfma_f32_16x16x32_f16(
                        af2[m][kk], bf[n][kk], acc[m + 2][n], 0, 0, 0);
        __builtin_amdgcn_s_setprio(0);
        __builtin_amdgcn_sched_barrier(0);

        // ---- group end: counted drain (never 0 mid-loop) ----
        if (g < 10) asm volatile("s_waitcnt vmcnt(6)" ::: "memory");
        else        asm volatile("s_waitcnt vmcnt(0)" ::: "memory");
        __builtin_amdgcn_sched_barrier(0);
        __builtin_amdgcn_s_barrier();
        __builtin_amdgcn_sched_barrier(0);
    }

    // -------- epilogue: d = fmaf(-2, acc*2^-13, S); argmin over 256 cols ----
    // C/D layout: col = lane&15, row = (lane>>4)*4 + reg  [verified round 3].
    float* dredf = (float*)smem;           // [128][4]  (buffers dead, all waves synced)
    int*   kredi = (int*)(smem + 2048);

    #pragma unroll
    for (int m = 0; m < 4; ++m) {
        #pragma unroll
        for (int reg = 0; reg < 4; ++reg) {
            const int rloc = wr * 64 + m * 16 + lhi * 4 + reg;
            const float Sv = S[m0 + rloc];
            float bd = 3.4e38f; int bk = 0x7fffffff;
            #pragma unroll
            for (int n = 0; n < 4; ++n) {
                float dot = acc[m][n][reg] * BSCALE_INV;
                float d = fmaf(-2.0f, dot, Sv);
                const int col = n0 + wc * 64 + n * 16 + lr;
                if (d < bd) { bd = d; bk = col; }          // ascending col
            }
            #pragma unroll
            for (int msk = 1; msk < 16; msk <<= 1) {
                float od = __shfl_xor(bd, msk, 64);
                int   ok = __shfl_xor(bk, msk, 64);
                if (od < bd || (od == bd && ok < bk)) { bd = od; bk = ok; }
            }
            if (lr == 0) { dredf[rloc * 4 + wc] = bd; kredi[rloc * 4 + wc] = bk; }
        }
    }
    __syncthreads();
    if (tid < 128) {
        float bd = dredf[tid * 4]; int bk = kredi[tid * 4];
        #pragma unroll
        for (int j = 1; j < 4; ++j) {                      // ascending wc = ascending cols
            float d = dredf[tid * 4 + j]; int k2 = kredi[tid * 4 + j];
            if (d < bd || (d == bd && k2 < bk)) { bd = d; bk = k2; }
        }
        pd[(size_t)bxt * TOK + m0 + tid] = bd;
        pi[(size_t)bxt * TOK + m0 + tid] = bk;
    }
}

// ---------------- final argmin across 32 col-tiles + histogram --------------
__global__ __launch_bounds__(256) void argmin_reduce_kernel(
        const float* __restrict__ pd, const int* __restrict__ pi,
        int* __restrict__ idx, unsigned* __restrict__ counts,
        float* __restrict__ out_idxf) {
    int n = blockIdx.x * 256 + threadIdx.x;
    float bestd = 3.4e38f;
    int   bestk = 0x7fffffff;
    for (int t = 0; t < NTILES_K; ++t) {
        float d = pd[(size_t)t * TOK + n];
        int   k = pi[(size_t)t * TOK + n];
        if (d < bestd || (d == bestd && k < bestk)) { bestd = d; bestk = k; }
    }
    idx[n] = bestk;
    out_idxf[n] = (float)bestk;
    atomicAdd(&counts[bestk], 1u);
}

// ---------------- one-hot fill (1GB, nontemporal stores) --------------------
__global__ __launch_bounds__(256) void onehot_fill_kernel(
        const int* __restrict__ idx, float* __restrict__ oh) {
    const size_t tid0 = (size_t)blockIdx.x * 256 + threadIdx.x;
    for (int it = 0; it < 32; ++it) {
        size_t e4 = tid0 + (size_t)it * 2097152;
        size_t f0 = e4 * 4;
        int n = (int)(f0 >> 13);
        int k = (int)(f0 & 8191);
        f32x4 z = {0.f, 0.f, 0.f, 0.f};
        int id = idx[n];
        int dlt = id - k;
        if (dlt >= 0 && dlt < 4) z[dlt] = 1.0f;
        __builtin_nontemporal_store(z, (f32x4*)(oh + f0));
    }
}

// ---------------- xq gather + loss sums (LDS-staged, coalesced) -------------
__global__ __launch_bounds__(256) void xq_loss_kernel(
        const float* __restrict__ x, const float* __restrict__ cb,
        const int* __restrict__ idx, float* __restrict__ xq,
        double* __restrict__ accum) {
    __shared__ float qs[64][65];
    __shared__ double r1s[4], r2s[4];
    const int n0 = blockIdx.x * 64;
    const int b = n0 >> 10, hw0 = n0 & 1023;
    const float* xb  = x  + (size_t)b * 262144 + hw0;
    float*       xqb = xq + (size_t)b * 262144 + hw0;
    const int cr = threadIdx.x >> 6, i = threadIdx.x & 63;
    const int tl = threadIdx.x >> 2, part = threadIdx.x & 3;
    const int myidx = idx[n0 + tl];
    double s1 = 0.0, s2 = 0.0;

    for (int ch = 0; ch < 4; ++ch) {
        const int c0 = ch * 64;
        __syncthreads();
        #pragma unroll
        for (int j = 0; j < 4; ++j) {
            float4 q = *(const float4*)(cb + (size_t)myidx * 256 + c0 + part * 16 + j * 4);
            qs[part * 16 + j * 4 + 0][tl] = q.x;
            qs[part * 16 + j * 4 + 1][tl] = q.y;
            qs[part * 16 + j * 4 + 2][tl] = q.z;
            qs[part * 16 + j * 4 + 3][tl] = q.w;
        }
        __syncthreads();
        #pragma unroll
        for (int j = 0; j < 16; ++j) {
            const int c = c0 + cr * 16 + j;
            float xv = xb[(size_t)c * 1024 + i];
            float qv = qs[cr * 16 + j][i];
            float t = qv - xv;
            xqb[(size_t)c * 1024 + i] = xv + t;   // exact STE replication
            float d = xv - qv;
            s1 += (double)d;
            s2 += (double)d * (double)d;
        }
    }

    #pragma unroll
    for (int m = 1; m < 64; m <<= 1) {
        s1 += __shfl_xor(s1, m, 64);
        s2 += __shfl_xor(s2, m, 64);
    }
    const int wv = threadIdx.x >> 6, ln = threadIdx.x & 63;
    if (ln == 0) { r1s[wv] = s1; r2s[wv] = s2; }
    __syncthreads();
    if (threadIdx.x == 0) {
        atomicAdd(&accum[0], r1s[0] + r1s[1] + r1s[2] + r1s[3]);
        atomicAdd(&accum[1], r2s[0] + r2s[1] + r2s[2] + r2s[3]);
    }
}

// ---------------- scalars ---------------------------------------------------
__global__ __launch_bounds__(256) void finalize_kernel(
        const unsigned* __restrict__ counts, const double* __restrict__ accum,
        float* __restrict__ out) {
    double h = 0.0;
    for (int k = threadIdx.x; k < KCB; k += 256) {
        float e = (float)counts[k] / 32768.0f;
        h += (double)(e * logf(e + 1e-10f));
    }
    #pragma unroll
    for (int m = 1; m < 64; m <<= 1) h += __shfl_xor(h, m, 64);
    __shared__ double rh[4];
    int wv = threadIdx.x >> 6, ln = threadIdx.x & 63;
    if (ln == 0) rh[wv] = h;
    __syncthreads();
    if (threadIdx.x == 0) {
        double H = rh[0] + rh[1] + rh[2] + rh[3];
        double m1 = accum[0] / 8388608.0;
        double m2 = accum[1] / 8388608.0;
        out[LOSS_OFF] = (float)(0.25 * m1 + m2);
        out[PERP_OFF] = expf((float)(-H));
    }
}

extern "C" void kernel_launch(void* const* d_in, const int* in_sizes, int n_in,
                              void* d_out, int out_size, void* d_ws, size_t ws_size,
                              hipStream_t stream) {
    const float* x  = (const float*)d_in[0];
    const float* cb = (const float*)d_in[1];
    float* out = (float*)d_out;
    char*  ws  = (char*)d_ws;

    float*    S      = (float*)ws;                 // 32768 f32
    int*      idx    = (int*)(ws + 131072);        // 32768 i32
    unsigned* counts = (unsigned*)(ws + 262144);   // 8192 u32
    double*   accum  = (double*)(ws + 294912);     // 2 f64

    float* out_xq   = out;
    float* out_oh   = out + OH_OFF;
    float* out_idxf = out + IDX_OFF;

    // Staging inside the dead one-hot region (consumed before onehot_fill).
    char* stg = (char*)d_out + ((((size_t)OH_OFF * 4) + 255) & ~(size_t)255);
    float*    pd  = (float*)stg;                         // 4 MB (32 x 32768)
    int*      pi  = (int*)(stg + (4u << 20));            // 4 MB
    _Float16* A16 = (_Float16*)(stg + (8u << 20));       // 32 MB [32768][512]
    _Float16* B16 = (_Float16*)(stg + (40u << 20));      // 8 MB  [8192][512]

    hipMemsetAsync(ws + 262144, 0, 32768 + 16, stream);  // counts + accum

    s_kernel<<<128, 256, 0, stream>>>(x, S);
    split_x_kernel<<<512, 256, 0, stream>>>(x, A16);
    split_cb_kernel<<<2048, 256, 0, stream>>>(cb, B16);
    dist_mfma_kernel<<<dim3(32, 256), 512, 0, stream>>>(A16, B16, S, pd, pi);
    argmin_reduce_kernel<<<128, 256, 0, stream>>>(pd, pi, idx, counts, out_idxf);
    onehot_fill_kernel<<<8192, 256, 0, stream>>>(idx, out_oh);
    xq_loss_kernel<<<512, 256, 0, stream>>>(x, cb, idx, out_xq, accum);
    finalize_kernel<<<1, 256, 0, stream>>>(counts, accum, out);
}

// Round 8
// 1919.933 us; speedup vs baseline: 1.0398x; 1.0398x over previous
//
#include <hip/hip_runtime.h>
#include <hip/hip_bf16.h>

// VQ-VAE VectorQuantizer forward, MI355X — round 8: single-phase K-group (1 barrier/group).
//
// Precision contract (validated: rounds 3 & 7 absmax = 0.0):
//  - argmin over d_k = fl(S - 2*dot_k)   [E_k vanishes: E_max=3.8e-6 < ulp(S)/2]
//  - dot via 3-product fp16 split (K_eff=768): err ~7e-9 abs << ulp(d)=3e-5
//  - dot = acc * 2^-13 exact (B pre-scaled by 2^13); S fp64-accumulated
//
// dist kernel (changed this round): per K-group, ONE phase and ONE barrier:
//   {issue 6 global_load_lds (K g+2) -> 16 ds_read_b128 (buf g) -> lgkmcnt(0)
//    -> 32 MFMA (setprio 1) -> vmcnt(6) -> s_barrier}
// Safety proof: staging targets buf (g+2)%3 == (g-1)%3; all reads of that buf
// happened in group g-1 and were drained by each wave's lgkmcnt(0) BEFORE the
// g-1 end-barrier; a wave is only in group g after that barrier. vmcnt ledger:
// 12 prologue loads -> vmcnt(6) => K0 landed; each group issues 6, ends
// vmcnt(6) => K(g+1) landed (FIFO); drain vmcnt(0) only at g>=10.

#define TOK   32768
#define KCB   8192
#define CDIM  256

#define LOSS_OFF   8388608
#define PERP_OFF   8388609
#define OH_OFF     8388610
#define OH_ELEMS   268435456
#define IDX_OFF    276824066

#define NTILES_K   32   // 8192/256 code tiles

typedef _Float16 f16x8 __attribute__((ext_vector_type(8)));
typedef _Float16 f16x4 __attribute__((ext_vector_type(4)));
typedef float    f32x4 __attribute__((ext_vector_type(4)));

#define BSCALE     8192.0f     // 2^13
#define BSCALE_INV 0x1p-13f

__device__ __forceinline__ void gload16(const void* g, void* l) {
    __builtin_amdgcn_global_load_lds(
        (const __attribute__((address_space(1))) void*)g,
        (__attribute__((address_space(3))) void*)l, 16, 0, 0);
}

// ---------------- x -> A16 [32768][512] fp16 (xhi | xlo) + fused S ----------
__global__ __launch_bounds__(256) void split_x_kernel(const float* __restrict__ x,
                                                      _Float16* __restrict__ A16,
                                                      float* __restrict__ S) {
    __shared__ float xs[64][65];
    const int n0 = blockIdx.x * 64;
    const int b = n0 >> 10, hw0 = n0 & 1023;
    const float* xb = x + (size_t)b * 262144 + hw0;
    const int cr = threadIdx.x >> 6, i = threadIdx.x & 63;
    const int tl = threadIdx.x >> 2, part = threadIdx.x & 3;
    double sacc = 0.0;

    for (int ch = 0; ch < 4; ++ch) {
        const int c0 = ch * 64;
        __syncthreads();
        #pragma unroll
        for (int j = 0; j < 16; ++j)
            xs[cr * 16 + j][i] = xb[(size_t)(c0 + cr * 16 + j) * 1024 + i];
        __syncthreads();
        f16x8 h0, h1, l0, l1;
        #pragma unroll
        for (int j = 0; j < 8; ++j) {
            float v = xs[part * 16 + j][tl];
            _Float16 h = (_Float16)v;
            h0[j] = h; l0[j] = (_Float16)(v - (float)h);
            sacc += (double)v * (double)v;
        }
        #pragma unroll
        for (int j = 0; j < 8; ++j) {
            float v = xs[part * 16 + 8 + j][tl];
            _Float16 h = (_Float16)v;
            h1[j] = h; l1[j] = (_Float16)(v - (float)h);
            sacc += (double)v * (double)v;
        }
        _Float16* dst = A16 + (size_t)(n0 + tl) * 512 + c0 + part * 16;
        *(f16x8*)(dst)           = h0;
        *(f16x8*)(dst + 8)       = h1;
        *(f16x8*)(dst + 256)     = l0;
        *(f16x8*)(dst + 256 + 8) = l1;
    }
    // 4 lanes (part 0..3, consecutive) hold this token's partial sums
    sacc += __shfl_xor(sacc, 1, 64);
    sacc += __shfl_xor(sacc, 2, 64);
    if (part == 0) S[n0 + tl] = (float)sacc;
}

// ---------------- cb -> B16 [8192][512] fp16 (ehi*2^13 | elo*2^13) ----------
__global__ __launch_bounds__(256) void split_cb_kernel(const float* __restrict__ cb,
                                                       _Float16* __restrict__ B16) {
    int t = blockIdx.x * 256 + threadIdx.x;
    int code = t >> 6, c = (t & 63) * 4;
    float4 v = *(const float4*)(cb + (size_t)code * 256 + c);
    float ev[4] = {v.x * BSCALE, v.y * BSCALE, v.z * BSCALE, v.w * BSCALE};
    f16x4 h, l;
    #pragma unroll
    for (int j = 0; j < 4; ++j) {
        _Float16 hh = (_Float16)ev[j];
        h[j] = hh; l[j] = (_Float16)(ev[j] - (float)hh);
    }
    *(f16x4*)(B16 + (size_t)code * 512 + c)       = h;
    *(f16x4*)(B16 + (size_t)code * 512 + 256 + c) = l;
}

// ---------------- MFMA distance GEMM + fused argmin -------------------------
__global__ __launch_bounds__(512, 2) void dist_mfma_kernel(
        const _Float16* __restrict__ A16, const _Float16* __restrict__ B16,
        const float* __restrict__ S,
        float* __restrict__ pd, int* __restrict__ pi) {
    __shared__ char smem[147456];          // 3 x (A 16KB + B 32KB)

    const int tid  = threadIdx.x;
    const int lane = tid & 63, w = tid >> 6;
    const int wr = w >> 2, wc = w & 3;     // 2 x 4 waves

    // XCD-aware bijective swizzle (nwg = 8192 = 8*1024)
    const int id  = (int)(blockIdx.y * gridDim.x + blockIdx.x);
    const int nid = (id & 7) * 1024 + (id >> 3);
    const int bxt = nid >> 8;              // code tile 0..31
    const int byt = nid & 255;             // token tile 0..255
    const int m0  = byt * 128;
    const int n0  = bxt * 256;

    const char* A16b = (const char*)A16;
    const char* B16b = (const char*)B16;

    // staging: thread stages 16B of row srow(+64k); source chunk inverse-swizzled
    const int srow     = tid >> 3;
    const int schunk16 = ((tid & 7) ^ (srow & 7)) << 4;

    const int lr  = lane & 15;
    const int l47 = lane & 7;
    const int lhi = lane >> 4;

    f32x4 acc[4][4] = {};

    // -------- prologue: stage K-steps 0 and 1 --------
    #pragma unroll
    for (int s = 0; s < 2; ++s) {
        const int aK2 = s * 128, bK2 = s * 128;   // steps 0,1 are hi|hi
        char* Ab = smem + s * 49152;
        char* Bb = Ab + 16384;
        gload16(A16b + (size_t)(m0 + srow)      * 1024 + aK2 + schunk16, Ab + tid * 16);
        gload16(A16b + (size_t)(m0 + 64 + srow) * 1024 + aK2 + schunk16, Ab + 8192 + tid * 16);
        #pragma unroll
        for (int i = 0; i < 4; ++i)
            gload16(B16b + (size_t)(n0 + i * 64 + srow) * 1024 + bK2 + schunk16,
                    Bb + i * 8192 + tid * 16);
    }
    asm volatile("s_waitcnt vmcnt(6)" ::: "memory");   // K0 landed
    __builtin_amdgcn_sched_barrier(0);
    __builtin_amdgcn_s_barrier();
    __builtin_amdgcn_sched_barrier(0);

    // -------- main loop: 12 K-steps, ONE phase + ONE barrier each --------
    #pragma unroll
    for (int g = 0; g < 12; ++g) {
        char* Ab = smem + (g % 3) * 49152;
        char* Bb = Ab + 16384;
        const int s2 = g + 2;

        // issue-early staging of K(g+2) into buf (g+2)%3 == (g-1)%3
        if (s2 < 12) {
            char* Ab2 = smem + (s2 % 3) * 49152;
            char* Bb2 = Ab2 + 16384;
            const int ph2 = s2 >> 2, rk2 = (s2 & 3) * 128;
            const int aK2 = (ph2 == 2 ? 512 : 0) + rk2;
            const int bK2 = (ph2 == 1 ? 512 : 0) + rk2;
            gload16(A16b + (size_t)(m0 + srow)      * 1024 + aK2 + schunk16, Ab2 + tid * 16);
            gload16(A16b + (size_t)(m0 + 64 + srow) * 1024 + aK2 + schunk16, Ab2 + 8192 + tid * 16);
            #pragma unroll
            for (int i = 0; i < 4; ++i)
                gload16(B16b + (size_t)(n0 + i * 64 + srow) * 1024 + bK2 + schunk16,
                        Bb2 + i * 8192 + tid * 16);
        }

        // register fragment loads (buf g): 8 B + 8 A ds_read_b128, swizzled
        f16x8 bf[4][2], af[4][2];
        #pragma unroll
        for (int n = 0; n < 4; ++n)
            #pragma unroll
            for (int kk = 0; kk < 2; ++kk) {
                const int row = wc * 64 + n * 16 + lr;
                bf[n][kk] = *(const f16x8*)(Bb + row * 128 + (((kk * 4 + lhi) ^ l47) << 4));
            }
        #pragma unroll
        for (int m = 0; m < 4; ++m)
            #pragma unroll
            for (int kk = 0; kk < 2; ++kk) {
                const int row = wr * 64 + m * 16 + lr;
                af[m][kk] = *(const f16x8*)(Ab + row * 128 + (((kk * 4 + lhi) ^ l47) << 4));
            }

        asm volatile("s_waitcnt lgkmcnt(0)" ::: "memory");
        __builtin_amdgcn_sched_barrier(0);
        __builtin_amdgcn_s_setprio(1);
        #pragma unroll
        for (int m = 0; m < 4; ++m)
            #pragma unroll
            for (int n = 0; n < 4; ++n)
                #pragma unroll
                for (int kk = 0; kk < 2; ++kk)
                    acc[m][n] = __builtin_amdgcn_mfma_f32_16x16x32_f16(
                        af[m][kk], bf[n][kk], acc[m][n], 0, 0, 0);
        __builtin_amdgcn_s_setprio(0);
        __builtin_amdgcn_sched_barrier(0);

        // group end: counted drain (never 0 mid-loop)
        if (g < 10) asm volatile("s_waitcnt vmcnt(6)" ::: "memory");
        else        asm volatile("s_waitcnt vmcnt(0)" ::: "memory");
        __builtin_amdgcn_sched_barrier(0);
        __builtin_amdgcn_s_barrier();
        __builtin_amdgcn_sched_barrier(0);
    }

    // -------- epilogue: d = fmaf(-2, acc*2^-13, S); argmin over 256 cols ----
    // C/D layout: col = lane&15, row = (lane>>4)*4 + reg  [verified rounds 3/7]
    float* dredf = (float*)smem;
    int*   kredi = (int*)(smem + 2048);

    #pragma unroll
    for (int m = 0; m < 4; ++m) {
        #pragma unroll
        for (int reg = 0; reg < 4; ++reg) {
            const int rloc = wr * 64 + m * 16 + lhi * 4 + reg;
            const float Sv = S[m0 + rloc];
            float bd = 3.4e38f; int bk = 0x7fffffff;
            #pragma unroll
            for (int n = 0; n < 4; ++n) {
                float dot = acc[m][n][reg] * BSCALE_INV;
                float d = fmaf(-2.0f, dot, Sv);
                const int col = n0 + wc * 64 + n * 16 + lr;
                if (d < bd) { bd = d; bk = col; }
            }
            #pragma unroll
            for (int msk = 1; msk < 16; msk <<= 1) {
                float od = __shfl_xor(bd, msk, 64);
                int   ok = __shfl_xor(bk, msk, 64);
                if (od < bd || (od == bd && ok < bk)) { bd = od; bk = ok; }
            }
            if (lr == 0) { dredf[rloc * 4 + wc] = bd; kredi[rloc * 4 + wc] = bk; }
        }
    }
    __syncthreads();
    if (tid < 128) {
        float bd = dredf[tid * 4]; int bk = kredi[tid * 4];
        #pragma unroll
        for (int j = 1; j < 4; ++j) {
            float d = dredf[tid * 4 + j]; int k2 = kredi[tid * 4 + j];
            if (d < bd || (d == bd && k2 < bk)) { bd = d; bk = k2; }
        }
        pd[(size_t)bxt * TOK + m0 + tid] = bd;
        pi[(size_t)bxt * TOK + m0 + tid] = bk;
    }
}

// ---------------- final argmin across 32 col-tiles + histogram --------------
__global__ __launch_bounds__(256) void argmin_reduce_kernel(
        const float* __restrict__ pd, const int* __restrict__ pi,
        int* __restrict__ idx, unsigned* __restrict__ counts,
        float* __restrict__ out_idxf) {
    int n = blockIdx.x * 256 + threadIdx.x;
    float bestd = 3.4e38f;
    int   bestk = 0x7fffffff;
    for (int t = 0; t < NTILES_K; ++t) {
        float d = pd[(size_t)t * TOK + n];
        int   k = pi[(size_t)t * TOK + n];
        if (d < bestd || (d == bestd && k < bestk)) { bestd = d; bestk = k; }
    }
    idx[n] = bestk;
    out_idxf[n] = (float)bestk;
    atomicAdd(&counts[bestk], 1u);
}

// ---------------- one-hot fill (1GB, nontemporal stores) --------------------
__global__ __launch_bounds__(256) void onehot_fill_kernel(
        const int* __restrict__ idx, float* __restrict__ oh) {
    const size_t tid0 = (size_t)blockIdx.x * 256 + threadIdx.x;
    for (int it = 0; it < 32; ++it) {
        size_t e4 = tid0 + (size_t)it * 2097152;
        size_t f0 = e4 * 4;
        int n = (int)(f0 >> 13);
        int k = (int)(f0 & 8191);
        f32x4 z = {0.f, 0.f, 0.f, 0.f};
        int id = idx[n];
        int dlt = id - k;
        if (dlt >= 0 && dlt < 4) z[dlt] = 1.0f;
        __builtin_nontemporal_store(z, (f32x4*)(oh + f0));
    }
}

// ---------------- xq gather + loss sums (LDS-staged, coalesced) -------------
__global__ __launch_bounds__(256) void xq_loss_kernel(
        const float* __restrict__ x, const float* __restrict__ cb,
        const int* __restrict__ idx, float* __restrict__ xq,
        double* __restrict__ accum) {
    __shared__ float qs[64][65];
    __shared__ double r1s[4], r2s[4];
    const int n0 = blockIdx.x * 64;
    const int b = n0 >> 10, hw0 = n0 & 1023;
    const float* xb  = x  + (size_t)b * 262144 + hw0;
    float*       xqb = xq + (size_t)b * 262144 + hw0;
    const int cr = threadIdx.x >> 6, i = threadIdx.x & 63;
    const int tl = threadIdx.x >> 2, part = threadIdx.x & 3;
    const int myidx = idx[n0 + tl];
    double s1 = 0.0, s2 = 0.0;

    for (int ch = 0; ch < 4; ++ch) {
        const int c0 = ch * 64;
        __syncthreads();
        #pragma unroll
        for (int j = 0; j < 4; ++j) {
            float4 q = *(const float4*)(cb + (size_t)myidx * 256 + c0 + part * 16 + j * 4);
            qs[part * 16 + j * 4 + 0][tl] = q.x;
            qs[part * 16 + j * 4 + 1][tl] = q.y;
            qs[part * 16 + j * 4 + 2][tl] = q.z;
            qs[part * 16 + j * 4 + 3][tl] = q.w;
        }
        __syncthreads();
        #pragma unroll
        for (int j = 0; j < 16; ++j) {
            const int c = c0 + cr * 16 + j;
            float xv = xb[(size_t)c * 1024 + i];
            float qv = qs[cr * 16 + j][i];
            float t = qv - xv;
            xqb[(size_t)c * 1024 + i] = xv + t;   // exact STE replication
            float d = xv - qv;
            s1 += (double)d;
            s2 += (double)d * (double)d;
        }
    }

    #pragma unroll
    for (int m = 1; m < 64; m <<= 1) {
        s1 += __shfl_xor(s1, m, 64);
        s2 += __shfl_xor(s2, m, 64);
    }
    const int wv = threadIdx.x >> 6, ln = threadIdx.x & 63;
    if (ln == 0) { r1s[wv] = s1; r2s[wv] = s2; }
    __syncthreads();
    if (threadIdx.x == 0) {
        atomicAdd(&accum[0], r1s[0] + r1s[1] + r1s[2] + r1s[3]);
        atomicAdd(&accum[1], r2s[0] + r2s[1] + r2s[2] + r2s[3]);
    }
}

// ---------------- scalars ---------------------------------------------------
__global__ __launch_bounds__(256) void finalize_kernel(
        const unsigned* __restrict__ counts, const double* __restrict__ accum,
        float* __restrict__ out) {
    double h = 0.0;
    for (int k = threadIdx.x; k < KCB; k += 256) {
        float e = (float)counts[k] / 32768.0f;
        h += (double)(e * logf(e + 1e-10f));
    }
    #pragma unroll
    for (int m = 1; m < 64; m <<= 1) h += __shfl_xor(h, m, 64);
    __shared__ double rh[4];
    int wv = threadIdx.x >> 6, ln = threadIdx.x & 63;
    if (ln == 0) rh[wv] = h;
    __syncthreads();
    if (threadIdx.x == 0) {
        double H = rh[0] + rh[1] + rh[2] + rh[3];
        double m1 = accum[0] / 8388608.0;
        double m2 = accum[1] / 8388608.0;
        out[LOSS_OFF] = (float)(0.25 * m1 + m2);
        out[PERP_OFF] = expf((float)(-H));
    }
}

extern "C" void kernel_launch(void* const* d_in, const int* in_sizes, int n_in,
                              void* d_out, int out_size, void* d_ws, size_t ws_size,
                              hipStream_t stream) {
    const float* x  = (const float*)d_in[0];
    const float* cb = (const float*)d_in[1];
    float* out = (float*)d_out;
    char*  ws  = (char*)d_ws;

    float*    S      = (float*)ws;                 // 32768 f32
    int*      idx    = (int*)(ws + 131072);        // 32768 i32
    unsigned* counts = (unsigned*)(ws + 262144);   // 8192 u32
    double*   accum  = (double*)(ws + 294912);     // 2 f64

    float* out_xq   = out;
    float* out_oh   = out + OH_OFF;
    float* out_idxf = out + IDX_OFF;

    // Staging inside the dead one-hot region (consumed before onehot_fill).
    char* stg = (char*)d_out + ((((size_t)OH_OFF * 4) + 255) & ~(size_t)255);
    float*    pd  = (float*)stg;                         // 4 MB (32 x 32768)
    int*      pi  = (int*)(stg + (4u << 20));            // 4 MB
    _Float16* A16 = (_Float16*)(stg + (8u << 20));       // 32 MB [32768][512]
    _Float16* B16 = (_Float16*)(stg + (40u << 20));      // 8 MB  [8192][512]

    hipMemsetAsync(ws + 262144, 0, 32768 + 16, stream);  // counts + accum

    split_x_kernel<<<512, 256, 0, stream>>>(x, A16, S);
    split_cb_kernel<<<2048, 256, 0, stream>>>(cb, B16);
    dist_mfma_kernel<<<dim3(32, 256), 512, 0, stream>>>(A16, B16, S, pd, pi);
    argmin_reduce_kernel<<<128, 256, 0, stream>>>(pd, pi, idx, counts, out_idxf);
    onehot_fill_kernel<<<8192, 256, 0, stream>>>(idx, out_oh);
    xq_loss_kernel<<<512, 256, 0, stream>>>(x, cb, idx, out_xq, accum);
    finalize_kernel<<<1, 256, 0, stream>>>(counts, accum, out);
}